// Round 12
// baseline (1316.895 us; speedup 1.0000x reference)
//
#include <hip/hip_runtime.h>
#include <hip/hip_bf16.h>
#include <cstdint>
#include <cstddef>

#define LSEQ   8192
#define DMODEL 2048
#define NH     16      // heads == groups
#define HD     128     // head dim == hidden dim
#define CH     2048    // chunk length (group-space positions)

typedef __attribute__((ext_vector_type(8))) __bf16 bf16x8;
typedef __attribute__((ext_vector_type(4))) float f32x4;

// ---------------------------------------------------------------- helpers

__device__ __forceinline__ float wave_sum64(float v) {
#pragma unroll
  for (int m = 32; m; m >>= 1) v += __shfl_xor(v, m, 64);
  return v;
}

__device__ __forceinline__ float sigm(float x) { return 1.0f / (1.0f + expf(-x)); }

// RTNE float -> bf16 bits
__device__ __forceinline__ unsigned short f2bf(float f) {
  unsigned int u = __float_as_uint(f);
  u += 0x7FFFu + ((u >> 16) & 1u);
  return (unsigned short)(u >> 16);
}
__device__ __forceinline__ float bf2f(unsigned short h) {
  return __uint_as_float((unsigned int)h << 16);
}

// async global->LDS, 16B per lane.
__device__ __forceinline__ void gload_lds16(const void* g, void* l) {
  __builtin_amdgcn_global_load_lds((__attribute__((address_space(1))) void*)(g),
                                   (__attribute__((address_space(3))) void*)(l), 16, 0, 0);
}

union bfu8 { bf16x8 v; unsigned short u[8]; };

// ---------------------------------------------------------------- casts

__global__ void k_cast(const float* __restrict__ X, unsigned short* __restrict__ Xb, int n4) {
  int i = blockIdx.x * 256 + threadIdx.x;
  int stride = gridDim.x * 256;
  for (; i < n4; i += stride) {
    float4 v = ((const float4*)X)[i];
    ushort4 o;
    o.x = f2bf(v.x); o.y = f2bf(v.y); o.z = f2bf(v.z); o.w = f2bf(v.w);
    ((ushort4*)Xb)[i] = o;
  }
}

// W (K x N, fp32) -> Wt (N x K, bf16). grid (N/64, K/64), block 256.
__global__ void k_tcast(const float* __restrict__ W, unsigned short* __restrict__ Wt,
                        int K, int N) {
  __shared__ float t[64][65];
  const int n0 = blockIdx.x * 64, k0 = blockIdx.y * 64;
  const int tid = threadIdx.x;
  const int cx = tid & 63, ry = tid >> 6;
#pragma unroll
  for (int r = 0; r < 16; ++r) {
    int row = ry + r * 4;
    t[row][cx] = W[(size_t)(k0 + row) * N + n0 + cx];
  }
  __syncthreads();
#pragma unroll
  for (int r = 0; r < 16; ++r) {
    int nn = ry + r * 4;
    Wt[(size_t)(n0 + nn) * K + k0 + cx] = f2bf(t[cx][nn]);
  }
}

// ---------------------------------------------------------------- bf16 MFMA GEMM core, BK=64 + XOR swizzle
// Staging: global_load_lds, linear LDS dest; source column-slot pre-swizzled per lane
// (rule #21: swizzle both sides - source permutation == read permutation).
// Tile [128 rows][64 cols] bf16 per operand (16KB). Frag reads are bank-conflict-free
// (2 lanes/bank). Barriers per 64-K (half of BK=32 version).

__device__ __forceinline__ void gemm_core64(const unsigned short* __restrict__ A,
                                            const unsigned short* __restrict__ B,
                                            int K, int ldA, int ldB, int row0, int col0,
                                            char* Al, char* Bl,
                                            f32x4 acc[4][4]) {
  const int tid = threadIdx.x;
  const int w = tid >> 6, l = tid & 63;
  const int lrow = l & 15, lg = l >> 4;     // frag row-in-16, col-slot base
  const int wr = (w >> 1) * 64, wc = (w & 1) * 64;
  const int srow8 = l >> 3;                 // row within 8-row staging chunk
  const int scol = ((l & 7) ^ srow8) * 8;   // pre-swizzled source col (bf16 units)

  for (int kk = 0; kk < K; kk += 64) {
#pragma unroll
    for (int q = 0; q < 4; ++q) {
      int c = w * 4 + q;                    // chunk 0..15 (8 rows, 1KB each)
      int row = c * 8 + srow8;              // row&7 == srow8 (c*8 = 0 mod 8)
      gload_lds16(A + (size_t)(row0 + row) * ldA + kk + scol, Al + c * 1024);
      gload_lds16(B + (size_t)(col0 + row) * ldB + kk + scol, Bl + c * 1024);
    }
    __syncthreads();
#pragma unroll
    for (int h = 0; h < 2; ++h) {
      bf16x8 af[4], bfr[4];
#pragma unroll
      for (int m = 0; m < 4; ++m) {
        int row = wr + m * 16 + lrow;
        af[m] = *(const bf16x8*)(Al + row * 128 + (((h * 4 + lg) ^ (row & 7)) << 4));
      }
#pragma unroll
      for (int n = 0; n < 4; ++n) {
        int row = wc + n * 16 + lrow;
        bfr[n] = *(const bf16x8*)(Bl + row * 128 + (((h * 4 + lg) ^ (row & 7)) << 4));
      }
#pragma unroll
      for (int m = 0; m < 4; ++m)
#pragma unroll
        for (int n = 0; n < 4; ++n)
          acc[m][n] = __builtin_amdgcn_mfma_f32_16x16x32_bf16(af[m], bfr[n], acc[m][n], 0, 0, 0);
    }
    __syncthreads();
  }
}

// ---------------------------------------------------------------- swizzled LDS helpers (bf16, 128-col rows)

__device__ __forceinline__ bf16x8 ld_sw(const unsigned short* base, int row, int kcol) {
  int byte = (row * 256 + kcol * 2) ^ ((row & 7) << 4);
  return *(const bf16x8*)((const char*)base + byte);
}
__device__ __forceinline__ void st_sw(unsigned short* base, int row, int col, unsigned short v) {
  int byte = (row * 256 + col * 2) ^ ((row & 7) << 4);
  *(unsigned short*)((char*)base + byte) = v;
}
__device__ __forceinline__ unsigned short ld_sw1(const unsigned short* base, int row, int col) {
  int byte = (row * 256 + col * 2) ^ ((row & 7) << 4);
  return *(const unsigned short*)((const char*)base + byte);
}

__device__ __forceinline__ void stage_sw(const float* __restrict__ src, int ld,
                                         unsigned short* dst, int tid) {
#pragma unroll
  for (int p = 0; p < 16; ++p) {
    int row = p * 8 + (tid >> 5);
    int col = (tid & 31) * 4;
    float4 v = *(const float4*)(src + (size_t)row * ld + col);
    int byte = (row * 256 + col * 2) ^ ((row & 7) << 4);
    unsigned short* d = (unsigned short*)((char*)dst + byte);
    d[0] = f2bf(v.x); d[1] = f2bf(v.y); d[2] = f2bf(v.z); d[3] = f2bf(v.w);
  }
}

__device__ __forceinline__ void stage_sw64(const float* __restrict__ src, int ld,
                                           unsigned short* dst, int tid) {
#pragma unroll
  for (int p = 0; p < 8; ++p) {
    int row = p * 8 + (tid >> 5);
    int col = (tid & 31) * 4;
    float4 v = *(const float4*)(src + (size_t)row * ld + col);
    int byte = (row * 256 + col * 2) ^ ((row & 7) << 4);
    unsigned short* d = (unsigned short*)((char*)dst + byte);
    d[0] = f2bf(v.x); d[1] = f2bf(v.y); d[2] = f2bf(v.z); d[3] = f2bf(v.w);
  }
}

__device__ __forceinline__ void stage_hl(const float* __restrict__ src, int ld,
                                         unsigned short* H, unsigned short* L, int tid) {
#pragma unroll
  for (int p = 0; p < 16; ++p) {
    int row = p * 8 + (tid >> 5);
    int col = (tid & 31) * 4;
    float4 v = *(const float4*)(src + (size_t)row * ld + col);
    int byte = (row * 256 + col * 2) ^ ((row & 7) << 4);
    unsigned short* h = (unsigned short*)((char*)H + byte);
    unsigned short* l = (unsigned short*)((char*)L + byte);
    const float* pv = (const float*)&v;
#pragma unroll
    for (int i = 0; i < 4; ++i) {
      unsigned short hi = f2bf(pv[i]);
      h[i] = hi;
      l[i] = f2bf(pv[i] - bf2f(hi));
    }
  }
}

__device__ __forceinline__ void stage_hl_1024(const float* __restrict__ src, int ld,
                                              unsigned short* H, unsigned short* L, int tid) {
#pragma unroll
  for (int p = 0; p < 4; ++p) {
    int row = p * 32 + (tid >> 5);
    int col = (tid & 31) * 4;
    float4 v = *(const float4*)(src + (size_t)row * ld + col);
    int byte = (row * 256 + col * 2) ^ ((row & 7) << 4);
    unsigned short* h = (unsigned short*)((char*)H + byte);
    unsigned short* l = (unsigned short*)((char*)L + byte);
    const float* pv = (const float*)&v;
#pragma unroll
    for (int i = 0; i < 4; ++i) {
      unsigned short hi = f2bf(pv[i]);
      h[i] = hi;
      l[i] = f2bf(pv[i] - bf2f(hi));
    }
  }
}

__device__ __forceinline__ void stage_hl_ts(const float* __restrict__ src, int ld,
                                            const float* __restrict__ lr,
                                            unsigned short* H, unsigned short* L, int tid) {
#pragma unroll
  for (int p = 0; p < 16; ++p) {
    int t = p * 8 + (tid >> 5);
    int d = (tid & 31) * 4;
    float4 v = *(const float4*)(src + (size_t)t * ld + d);
    float sc = lr[t];
    const float* pv = (const float*)&v;
#pragma unroll
    for (int i = 0; i < 4; ++i) {
      float x = pv[i] * sc;
      unsigned short hi = f2bf(x);
      st_sw(H, d + i, t, hi);
      st_sw(L, d + i, t, f2bf(x - bf2f(hi)));
    }
  }
}

// ---------------------------------------------------------------- init w + row norms (+ w1^T copy)

__global__ void k_init_w(const float* __restrict__ w0, const float* __restrict__ w1,
                         const float* __restrict__ w2, float* __restrict__ WW,
                         float* __restrict__ WN0, float* __restrict__ W1T) {
  int rid = blockIdx.x;
  int m = rid >> 11;
  int gr = rid & 2047;
  const float* src = (m == 0) ? w0 : (m == 1) ? w1 : w2;
  const float* row = src + (size_t)gr * HD;
  float* drow = WW + ((size_t)m * 2048 + gr) * HD;
  int l = threadIdx.x;
  float v0 = row[l], v1 = row[l + 64];
  drow[l] = v0; drow[l + 64] = v1;
  if (m == 1) {
    int g = gr >> 7, r = gr & 127;
    W1T[((size_t)g * 128 + l) * 128 + r] = v0;
    W1T[((size_t)g * 128 + l + 64) * 128 + r] = v1;
  }
  float s = wave_sum64(v0 * v0 + v1 * v1);
  if (l == 0) WN0[rid] = sqrtf(s);
}

// ---------------------------------------------------------------- qkv projection (bf16 MFMA + fused silu/l2norm)

__global__ __launch_bounds__(256) void k_qkv_mfma(const unsigned short* __restrict__ xb,
                                                  const unsigned short* __restrict__ Wqt,
                                                  float* __restrict__ Q, float* __restrict__ Km,
                                                  float* __restrict__ V) {
  __shared__ __align__(16) char Al[16384];
  __shared__ __align__(16) char Bl[16384];
  __shared__ float nrm[128][2];
  const int bx = blockIdx.x, ct = blockIdx.y;

  f32x4 acc[4][4];
#pragma unroll
  for (int m = 0; m < 4; ++m)
#pragma unroll
    for (int n = 0; n < 4; ++n) acc[m][n] = {};

  gemm_core64(xb, Wqt, DMODEL, DMODEL, DMODEL, bx * 128, ct * 128, Al, Bl, acc);

  const int hh = ct / 3, which = ct % 3;
  float* dst = (which == 0) ? Q : (which == 1) ? Km : V;
  const int tid = threadIdx.x, w = tid >> 6, l = tid & 63;
  const int wr = (w >> 1) * 64, wc = (w & 1) * 64;

#pragma unroll
  for (int m = 0; m < 4; ++m)
#pragma unroll
    for (int n = 0; n < 4; ++n)
#pragma unroll
      for (int j = 0; j < 4; ++j) {
        float v = acc[m][n][j];
        acc[m][n][j] = v * sigm(v);
      }

  float f[4][4];
  if (which != 2) {
#pragma unroll
    for (int m = 0; m < 4; ++m)
#pragma unroll
      for (int j = 0; j < 4; ++j) {
        float p = 0.0f;
#pragma unroll
        for (int n = 0; n < 4; ++n) p = fmaf(acc[m][n][j], acc[m][n][j], p);
        p += __shfl_xor(p, 1, 64);
        p += __shfl_xor(p, 2, 64);
        p += __shfl_xor(p, 4, 64);
        p += __shfl_xor(p, 8, 64);
        f[m][j] = p;
      }
    if ((l & 15) == 0) {
#pragma unroll
      for (int m = 0; m < 4; ++m)
#pragma unroll
        for (int j = 0; j < 4; ++j)
          nrm[wr + m * 16 + (l >> 4) * 4 + j][w & 1] = f[m][j];
    }
    __syncthreads();
#pragma unroll
    for (int m = 0; m < 4; ++m)
#pragma unroll
      for (int j = 0; j < 4; ++j) {
        int row = wr + m * 16 + (l >> 4) * 4 + j;
        f[m][j] = 1.0f / (sqrtf(nrm[row][0] + nrm[row][1]) + 1e-5f);
      }
  } else {
#pragma unroll
    for (int m = 0; m < 4; ++m)
#pragma unroll
      for (int j = 0; j < 4; ++j) f[m][j] = 1.0f;
  }

#pragma unroll
  for (int m = 0; m < 4; ++m)
#pragma unroll
    for (int j = 0; j < 4; ++j) {
      int t = bx * 128 + wr + m * 16 + (l >> 4) * 4 + j;
      int fth = t * NH + hh;
      int g = fth >> 13, tp = fth & 8191;
      float* drow = dst + ((size_t)g * LSEQ + tp) * HD;
#pragma unroll
      for (int n = 0; n < 4; ++n)
        drow[wc + n * 16 + (l & 15)] = acc[m][n][j] * f[m][j];
    }
}

// ---------------------------------------------------------------- lr / scale: K-split GEMM + reduce

__global__ __launch_bounds__(256) void k_lrms5(const float* __restrict__ x,
                                               const float* __restrict__ Wlr,
                                               const float* __restrict__ Wsc,
                                               float* __restrict__ P) {
  __shared__ float Xs[128][67];
  __shared__ float Ws[128][68];
  const int tb = blockIdx.x;
  const int kp = blockIdx.y;
  const int tid = threadIdx.x;
  for (int i = tid; i < 128 * 64; i += 256) {
    int k = i >> 6, c = i & 63;
    float wv = (c < 48) ? Wlr[(size_t)(kp * 128 + k) * 48 + c]
                        : Wsc[(size_t)(kp * 128 + k) * 16 + (c - 48)];
    Ws[k][c] = wv;
  }
  const int t8 = tid >> 5, kk = tid & 31;
#pragma unroll
  for (int r = 0; r < 8; ++r) {
    int t = t8 + r * 8;
    float4 v = *(const float4*)(x + (size_t)(tb * 64 + t) * DMODEL + kp * 128 + kk * 4);
    Xs[kk * 4 + 0][t] = v.x; Xs[kk * 4 + 1][t] = v.y;
    Xs[kk * 4 + 2][t] = v.z; Xs[kk * 4 + 3][t] = v.w;
  }
  __syncthreads();
  const int ty = tid >> 4, tx = tid & 15;
  float acc[4][4];
#pragma unroll
  for (int i = 0; i < 4; ++i)
#pragma unroll
    for (int j = 0; j < 4; ++j) acc[i][j] = 0.0f;
  for (int k = 0; k < 128; ++k) {
    float a[4], b[4];
#pragma unroll
    for (int i = 0; i < 4; ++i) a[i] = Xs[k][ty * 4 + i];
#pragma unroll
    for (int j = 0; j < 4; ++j) b[j] = Ws[k][tx * 4 + j];
#pragma unroll
    for (int i = 0; i < 4; ++i)
#pragma unroll
      for (int j = 0; j < 4; ++j) acc[i][j] = fmaf(a[i], b[j], acc[i][j]);
  }
  float* o = P + ((size_t)tb * 16 + kp) * 4096;
#pragma unroll
  for (int i = 0; i < 4; ++i)
#pragma unroll
    for (int j = 0; j < 4; ++j)
      o[(ty * 4 + i) * 64 + tx * 4 + j] = acc[i][j];
}

__global__ void k_lrsum(const float* __restrict__ P, const float* __restrict__ bs,
                        float* __restrict__ LR, float* __restrict__ SCL) {
  int e = blockIdx.x * 256 + threadIdx.x;
  int t = e >> 6, c = e & 63;
  const float* base = P + ((size_t)(t >> 6) * 16) * 4096 + (t & 63) * 64 + c;
  float sum = 0.0f;
#pragma unroll
  for (int kp = 0; kp < 16; ++kp) sum += base[(size_t)kp * 4096];
  if (c < 48) {
    float base_lr_inv = 0.01f + logf(-expm1f(-0.01f));
    float v = sum + base_lr_inv;
    float sp = fmaxf(v, 0.0f) + log1pf(expf(-fabsf(v)));
    LR[(size_t)c * LSEQ + t] = sp;
  } else {
    float v = sum + bs[c - 48];
    SCL[(size_t)(c - 48) * LSEQ + t] = v * sigm(v);
  }
}

// ---------------------------------------------------------------- per-chunk output (bf16 MFMA + fused LN/scale)

__global__ __launch_bounds__(256) void k_out2(const float* __restrict__ WW,
                                              const float* __restrict__ Q,
                                              const float* __restrict__ SCL,
                                              const float* __restrict__ lng,
                                              const float* __restrict__ lnb,
                                              unsigned short* __restrict__ U, int s) {
  __shared__ __align__(16) char smem[81920];
  unsigned short* Qs  = (unsigned short*)smem;
  unsigned short* W0s = (unsigned short*)(smem + 16384);
  unsigned short* W2s = (unsigned short*)(smem + 49152);
  float* Os = (float*)(smem + 16384);

  const int g = blockIdx.y;
  const int t0 = blockIdx.x * 64;
  const int tid = threadIdx.x;
  const int w = tid >> 6, l = tid & 63;
  const int lrow = l & 15, lk8 = (l >> 4) * 8;
  const int wr = (w >> 1) * 32, wc = (w & 1) * 64;

  const float* Qg  = Q + ((size_t)g * LSEQ + s + t0) * HD;
  const float* w0g = WW + ((size_t)0 * 2048 + g * 128) * 128;
  const float* w1g = WW + ((size_t)1 * 2048 + g * 128) * 128;
  const float* w2g = WW + ((size_t)2 * 2048 + g * 128) * 128;

  stage_sw64(Qg, HD, Qs, tid);
  stage_sw(w0g, 128, W0s, tid);
  stage_sw(w2g, 128, W2s, tid);
  __syncthreads();

  f32x4 ga[2][4], ha[2][4];
#pragma unroll
  for (int m = 0; m < 2; ++m)
#pragma unroll
    for (int n = 0; n < 4; ++n) { ga[m][n] = {}; ha[m][n] = {}; }
#pragma unroll
  for (int kk = 0; kk < 128; kk += 32) {
    bf16x8 af[2], b0[4], b2[4];
#pragma unroll
    for (int m = 0; m < 2; ++m) af[m] = ld_sw(Qs, wr + m * 16 + lrow, kk + lk8);
#pragma unroll
    for (int n = 0; n < 4; ++n) {
      b0[n] = ld_sw(W0s, wc + n * 16 + lrow, kk + lk8);
      b2[n] = ld_sw(W2s, wc + n * 16 + lrow, kk + lk8);
    }
#pragma unroll
    for (int m = 0; m < 2; ++m)
#pragma unroll
      for (int n = 0; n < 4; ++n) {
        ga[m][n] = __builtin_amdgcn_mfma_f32_16x16x32_bf16(af[m], b0[n], ga[m][n], 0, 0, 0);
        ha[m][n] = __builtin_amdgcn_mfma_f32_16x16x32_bf16(af[m], b2[n], ha[m][n], 0, 0, 0);
      }
  }
  __syncthreads();
#pragma unroll
  for (int m = 0; m < 2; ++m)
#pragma unroll
    for (int n = 0; n < 4; ++n)
#pragma unroll
      for (int j = 0; j < 4; ++j) {
        int row = wr + m * 16 + (l >> 4) * 4 + j;
        int col = wc + n * 16 + (l & 15);
        float gv = ga[m][n][j];
        st_sw(Qs, row, col, f2bf(gv * sigm(gv) * ha[m][n][j]));
      }
  stage_sw(w1g, 128, W0s, tid);
  __syncthreads();

  f32x4 oa[2][4];
#pragma unroll
  for (int m = 0; m < 2; ++m)
#pragma unroll
    for (int n = 0; n < 4; ++n) oa[m][n] = {};
#pragma unroll
  for (int kk = 0; kk < 128; kk += 32) {
    bf16x8 af[2], b1[4];
#pragma unroll
    for (int m = 0; m < 2; ++m) af[m] = ld_sw(Qs, wr + m * 16 + lrow, kk + lk8);
#pragma unroll
    for (int n = 0; n < 4; ++n) b1[n] = ld_sw(W0s, wc + n * 16 + lrow, kk + lk8);
#pragma unroll
    for (int m = 0; m < 2; ++m)
#pragma unroll
      for (int n = 0; n < 4; ++n)
        oa[m][n] = __builtin_amdgcn_mfma_f32_16x16x32_bf16(af[m], b1[n], oa[m][n], 0, 0, 0);
  }
  __syncthreads();
#pragma unroll
  for (int m = 0; m < 2; ++m)
#pragma unroll
    for (int n = 0; n < 4; ++n)
#pragma unroll
      for (int j = 0; j < 4; ++j) {
        int row = wr + m * 16 + (l >> 4) * 4 + j;
        int col = wc + n * 16 + (l & 15);
        Os[row * 132 + col] = oa[m][n][j];
      }
  __syncthreads();

  const int tok = tid >> 2, part = tid & 3;
  const float* orow = Os + tok * 132 + part * 32;
  float sum = 0.0f;
#pragma unroll
  for (int q = 0; q < 8; ++q) {
    float4 v = *(const float4*)(orow + q * 4);
    sum += (v.x + v.y) + (v.z + v.w);
  }
  sum += __shfl_xor(sum, 1, 64);
  sum += __shfl_xor(sum, 2, 64);
  float mu = sum * (1.0f / 128.0f);
  float vs = 0.0f;
#pragma unroll
  for (int q = 0; q < 8; ++q) {
    float4 v = *(const float4*)(orow + q * 4);
    float d0 = v.x - mu, d1 = v.y - mu, d2 = v.z - mu, d3 = v.w - mu;
    vs += d0 * d0 + d1 * d1 + d2 * d2 + d3 * d3;
  }
  vs += __shfl_xor(vs, 1, 64);
  vs += __shfl_xor(vs, 2, 64);
  float rstd = rsqrtf(vs * (1.0f / 128.0f) + 1e-6f);
  int tabs = s + t0 + tok;
  float sc = SCL[(size_t)g * LSEQ + tabs];
  unsigned short* urow = U + (size_t)tabs * DMODEL + g * HD + part * 32;
#pragma unroll
  for (int q = 0; q < 8; ++q) {
    float4 v = *(const float4*)(orow + q * 4);
    int d = part * 32 + q * 4;
    ushort4 o;
    o.x = f2bf(((v.x - mu) * rstd * lng[d + 0] + lnb[d + 0]) * sc);
    o.y = f2bf(((v.y - mu) * rstd * lng[d + 1] + lnb[d + 1]) * sc);
    o.z = f2bf(((v.z - mu) * rstd * lng[d + 2] + lnb[d + 2]) * sc);
    o.w = f2bf(((v.w - mu) * rstd * lng[d + 3] + lnb[d + 3]) * sc);
    *(ushort4*)(urow + q * 4) = o;
  }
}

// ---------------------------------------------------------------- fused front GEMMs + elementwise

__global__ __launch_bounds__(1024) void k_fe(const float* __restrict__ WW,
                                             const float* __restrict__ W1T,
                                             const float* __restrict__ Km,
                                             const float* __restrict__ V,
                                             float* __restrict__ BUF, int s) {
  __shared__ __align__(16) char smem[131072];
  unsigned short* KH = (unsigned short*)smem;
  unsigned short* KL = (unsigned short*)(smem + 32768);
  unsigned short* VH = (unsigned short*)(smem + 65536);
  unsigned short* VL = (unsigned short*)(smem + 98304);

  const int tt0 = blockIdx.x * 128;
  const int g = blockIdx.y;
  const int tid = threadIdx.x;
  const int w = tid >> 6, l = tid & 63;
  const int ww = w >> 2, wv = w & 3;
  const int lrow = l & 15, lk8 = (l >> 4) * 8;
  const int frow = (l >> 4) * 4, fcol = l & 15;

  stage_hl_1024(Km + ((size_t)g * LSEQ + s + tt0) * HD, HD, KH, KL, tid);
  stage_hl_1024(V + ((size_t)g * LSEQ + s + tt0) * HD, HD, VH, VL, tid);
  __syncthreads();

  const float* Asrc[3];
  Asrc[0] = WW + ((size_t)0 * 2048 + g * 128) * 128;
  Asrc[1] = WW + ((size_t)2 * 2048 + g * 128) * 128;
  Asrc[2] = W1T + (size_t)g * 16384;

  f32x4 acc[3][2][2];
#pragma unroll
  for (int q = 0; q < 3; ++q)
#pragma unroll
    for (int m = 0; m < 2; ++m)
#pragma unroll
      for (int n = 0; n < 2; ++n) acc[q][m][n] = {};

#pragma unroll 1
  for (int q = 0; q < 3; ++q) {
    const float* src = Asrc[q];
    const unsigned short* BH = (q == 2) ? VH : KH;
    const unsigned short* BL = (q == 2) ? VL : KL;
#pragma unroll
    for (int kk = 0; kk < 128; kk += 32) {
      bf16x8 ah[2], al[2], bh[2], bl[2];
#pragma unroll
      for (int m = 0; m < 2; ++m) {
        int row = ww * 32 + m * 16 + lrow;
        float4 v0 = *(const float4*)(src + (size_t)row * 128 + kk + lk8);
        float4 v1 = *(const float4*)(src + (size_t)row * 128 + kk + lk8 + 4);
        bfu8 h, lo;
        const float* p0 = (const float*)&v0;
        const float* p1 = (const float*)&v1;
#pragma unroll
        for (int i = 0; i < 4; ++i) {
          unsigned short hb0 = f2bf(p0[i]);
          h.u[i] = hb0; lo.u[i] = f2bf(p0[i] - bf2f(hb0));
          unsigned short hb1 = f2bf(p1[i]);
          h.u[i + 4] = hb1; lo.u[i + 4] = f2bf(p1[i] - bf2f(hb1));
        }
        ah[m] = h.v; al[m] = lo.v;
      }
#pragma unroll
      for (int n = 0; n < 2; ++n) {
        int row = wv * 32 + n * 16 + lrow;
        bh[n] = ld_sw(BH, row, kk + lk8);
        bl[n] = ld_sw(BL, row, kk + lk8);
      }
#pragma unroll
      for (int m = 0; m < 2; ++m)
#pragma unroll
        for (int n = 0; n < 2; ++n) {
          acc[q][m][n] = __builtin_amdgcn_mfma_f32_16x16x32_bf16(ah[m], bh[n], acc[q][m][n], 0, 0, 0);
          acc[q][m][n] = __builtin_amdgcn_mfma_f32_16x16x32_bf16(ah[m], bl[n], acc[q][m][n], 0, 0, 0);
          acc[q][m][n] = __builtin_amdgcn_mfma_f32_16x16x32_bf16(al[m], bh[n], acc[q][m][n], 0, 0, 0);
        }
    }
  }

  float* out0 = BUF + (size_t)0 * (NH * 128 * CH) + (size_t)g * 128 * CH;
  float* out1 = BUF + (size_t)1 * (NH * 128 * CH) + (size_t)g * 128 * CH;
  float* out2 = BUF + (size_t)2 * (NH * 128 * CH) + (size_t)g * 128 * CH;
#pragma unroll
  for (int m = 0; m < 2; ++m)
#pragma unroll
    for (int n = 0; n < 2; ++n)
#pragma unroll
      for (int j = 0; j < 4; ++j) {
        int row = ww * 32 + m * 16 + frow + j;
        int col = wv * 32 + n * 16 + fcol;
        float gb = acc[0][m][n][j];
        float hb = acc[1][m][n][j];
        float dh = acc[2][m][n][j];
        float sg = sigm(gb);
        float sgb = gb * sg;
        float hid = sgb * hb;
        float dgate = dh * hb;
        float dgb = dgate * sg * (1.0f + gb * (1.0f - sg));
        float dhb = dh * sgb;
        size_t o = (size_t)row * CH + tt0 + col;
        out0[o] = hid; out1[o] = dgb; out2[o] = dhb;
      }
}

// partial dW GEMMs over 256-token slices (split-bf16). grid (8, NH, 3).
__global__ __launch_bounds__(256) void k_dwp_mx(const float* __restrict__ BUF,
                                                const float* __restrict__ Km,
                                                const float* __restrict__ V,
                                                const float* __restrict__ LR,
                                                float* __restrict__ DWP, int s) {
  __shared__ __align__(16) char smem[131072];
  unsigned short* AH = (unsigned short*)smem;
  unsigned short* AL = (unsigned short*)(smem + 32768);
  unsigned short* BH = (unsigned short*)(smem + 65536);
  unsigned short* BL = (unsigned short*)(smem + 98304);

  const int p = blockIdx.x;
  const int g = blockIdx.y;
  const int z = blockIdx.z;
  const int tid = threadIdx.x;
  const int w = tid >> 6, l = tid & 63;
  const int lrow = l & 15, lk8 = (l >> 4) * 8;
  const int wr = (w >> 1) * 64, wc = (w & 1) * 64;

  const int msel = (z == 0) ? 1 : (z == 1) ? 0 : 2;
  const float* M = BUF + (size_t)msel * (NH * 128 * CH) + (size_t)g * 128 * CH;
  const float* N = (z == 1) ? V : Km;
  const float* lr = LR + (size_t)(z * NH + g) * LSEQ;
  const int ts = p * 256;

  f32x4 acc[4][4];
#pragma unroll
  for (int m = 0; m < 4; ++m)
#pragma unroll
    for (int n = 0; n < 4; ++n) acc[m][n] = {};

  for (int h = 0; h < 2; ++h) {
    if (h) __syncthreads();
    stage_hl(M + ts + h * 128, CH, AH, AL, tid);
    stage_hl_ts(N + ((size_t)g * LSEQ + s + ts + h * 128) * HD, HD,
                lr + s + ts + h * 128, BH, BL, tid);
    __syncthreads();
#pragma unroll
    for (int kk = 0; kk < 128; kk += 32) {
      bf16x8 ah[4], al4[4], bh[4], bl4[4];
#pragma unroll
      for (int m = 0; m < 4; ++m) {
        ah[m] = ld_sw(AH, wr + m * 16 + lrow, kk + lk8);
        al4[m] = ld_sw(AL, wr + m * 16 + lrow, kk + lk8);
      }
#pragma unroll
      for (int n = 0; n < 4; ++n) {
        bh[n] = ld_sw(BH, wc + n * 16 + lrow, kk + lk8);
        bl4[n] = ld_sw(BL, wc + n * 16 + lrow, kk + lk8);
      }
#pragma unroll
      for (int m = 0; m < 4; ++m)
#pragma unroll
        for (int n = 0; n < 4; ++n) {
          acc[m][n] = __builtin_amdgcn_mfma_f32_16x16x32_bf16(ah[m], bh[n], acc[m][n], 0, 0, 0);
          acc[m][n] = __builtin_amdgcn_mfma_f32_16x16x32_bf16(ah[m], bl4[n], acc[m][n], 0, 0, 0);
          acc[m][n] = __builtin_amdgcn_mfma_f32_16x16x32_bf16(al4[m], bh[n], acc[m][n], 0, 0, 0);
        }
    }
  }

  float* outp = DWP + (((size_t)(z * NH + g)) * 8 + p) * 16384;
#pragma unroll
  for (int m = 0; m < 4; ++m)
#pragma unroll
    for (int n = 0; n < 4; ++n)
#pragma unroll
      for (int j = 0; j < 4; ++j) {
        int row = wr + m * 16 + (l >> 4) * 4 + j;
        int col = wc + n * 16 + (l & 15);
        outp[row * 128 + col] = acc[m][n][j];
      }
}

// ---------------------------------------------------------------- Newton-Schulz 5 + fused w-update
__global__ __launch_bounds__(1024) void k_ns5_mfma(const float* __restrict__ DWP,
                                                   float* __restrict__ WW,
                                                   const float* __restrict__ WN0,
                                                   float* __restrict__ W1T) {
  __shared__ __align__(16) char smem[131072];
  unsigned short* PH = (unsigned short*)smem;
  unsigned short* PL = (unsigned short*)(smem + 32768);
  unsigned short* QH = (unsigned short*)(smem + 65536);
  unsigned short* QL = (unsigned short*)(smem + 98304);
  float* red = (float*)(smem + 65536);

  const float NA[5] = {4.0848f, 3.9505f, 3.7418f, 2.8769f, 2.8366f};
  const float NB[5] = {-6.8946f, -6.3029f, -5.5913f, -3.1427f, -3.0525f};
  const float NC[5] = {2.927f, 2.6377f, 2.3037f, 1.2046f, 1.2012f};
  const int zg = blockIdx.x;
  const int z = zg >> 4;
  const float* base = DWP + (size_t)zg * 8 * 16384;
  const int tid = threadIdx.x;
  const int w = tid >> 6, l = tid & 63;
  const int ww = w >> 2, wv = w & 3;
  const int lrow = l & 15, lk8 = (l >> 4) * 8;
  const int frow = (l >> 4) * 4, fcol = l & 15;

  float vals[16];
  float psum = 0.0f;
#pragma unroll
  for (int r = 0; r < 16; ++r) {
    int idx = tid + r * 1024;
    float sv = 0.0f;
#pragma unroll
    for (int p = 0; p < 8; ++p) sv += base[(size_t)p * 16384 + idx];
    vals[r] = sv;
    psum = fmaf(sv, sv, psum);
  }
  psum = wave_sum64(psum);
  if (l == 0) red[w] = psum;
  __syncthreads();
  float tot = 0.0f;
#pragma unroll
  for (int i = 0; i < 16; ++i) tot += red[i];
  float scl = 1.0f / (sqrtf(tot) + 1e-7f);
  __syncthreads();
#pragma unroll
  for (int r = 0; r < 16; ++r) {
    int idx = tid + r * 1024;
    int rr = idx >> 7, cc = idx & 127;
    float v = vals[r] * scl;
    unsigned short hi = f2bf(v);
    st_sw(PH, rr, cc, hi);
    st_sw(PL, rr, cc, f2bf(v - bf2f(hi)));
  }
  __syncthreads();

#pragma unroll 1
  for (int it = 0; it < 5; ++it) {
    const float ac = NA[it], bc = NB[it], cc2 = NC[it];

    f32x4 accA[2][2];
#pragma unroll
    for (int m = 0; m < 2; ++m)
#pragma unroll
      for (int n = 0; n < 2; ++n) accA[m][n] = {};
#pragma unroll
    for (int kk = 0; kk < 128; kk += 32) {
      bf16x8 ah[2], al[2], bh[2], bl[2];
#pragma unroll
      for (int m = 0; m < 2; ++m) {
        ah[m] = ld_sw(PH, ww * 32 + m * 16 + lrow, kk + lk8);
        al[m] = ld_sw(PL, ww * 32 + m * 16 + lrow, kk + lk8);
      }
#pragma unroll
      for (int n = 0; n < 2; ++n) {
        bh[n] = ld_sw(PH, wv * 32 + n * 16 + lrow, kk + lk8);
        bl[n] = ld_sw(PL, wv * 32 + n * 16 + lrow, kk + lk8);
      }
#pragma unroll
      for (int m = 0; m < 2; ++m)
#pragma unroll
        for (int n = 0; n < 2; ++n) {
          accA[m][n] = __builtin_amdgcn_mfma_f32_16x16x32_bf16(ah[m], bh[n], accA[m][n], 0, 0, 0);
          accA[m][n] = __builtin_amdgcn_mfma_f32_16x16x32_bf16(ah[m], bl[n], accA[m][n], 0, 0, 0);
          accA[m][n] = __builtin_amdgcn_mfma_f32_16x16x32_bf16(al[m], bh[n], accA[m][n], 0, 0, 0);
        }
    }
#pragma unroll
    for (int m = 0; m < 2; ++m)
#pragma unroll
      for (int n = 0; n < 2; ++n)
#pragma unroll
        for (int j = 0; j < 4; ++j) {
          int row = ww * 32 + m * 16 + frow + j;
          int col = wv * 32 + n * 16 + fcol;
          float v = accA[m][n][j];
          unsigned short hi = f2bf(v);
          st_sw(QH, row, col, hi);
          st_sw(QL, row, col, f2bf(v - bf2f(hi)));
        }
    __syncthreads();

    f32x4 accB[2][2];
#pragma unroll
    for (int m = 0; m < 2; ++m)
#pragma unroll
      for (int n = 0; n < 2; ++n) accB[m][n] = {};
#pragma unroll
    for (int kk = 0; kk < 128; kk += 32) {
      bf16x8 ah[2], al[2], bh[2], bl[2];
#pragma unroll
      for (int m = 0; m < 2; ++m) {
        ah[m] = ld_sw(QH, ww * 32 + m * 16 + lrow, kk + lk8);
        al[m] = ld_sw(QL, ww * 32 + m * 16 + lrow, kk + lk8);
      }
#pragma unroll
      for (int n = 0; n < 2; ++n) {
        bh[n] = ld_sw(QH, wv * 32 + n * 16 + lrow, kk + lk8);
        bl[n] = ld_sw(QL, wv * 32 + n * 16 + lrow, kk + lk8);
      }
#pragma unroll
      for (int m = 0; m < 2; ++m)
#pragma unroll
        for (int n = 0; n < 2; ++n) {
          accB[m][n] = __builtin_amdgcn_mfma_f32_16x16x32_bf16(ah[m], bh[n], accB[m][n], 0, 0, 0);
          accB[m][n] = __builtin_amdgcn_mfma_f32_16x16x32_bf16(ah[m], bl[n], accB[m][n], 0, 0, 0);
          accB[m][n] = __builtin_amdgcn_mfma_f32_16x16x32_bf16(al[m], bh[n], accB[m][n], 0, 0, 0);
        }
    }
#pragma unroll
    for (int m = 0; m < 2; ++m)
#pragma unroll
      for (int n = 0; n < 2; ++n)
#pragma unroll
        for (int j = 0; j < 4; ++j)
          accB[m][n][j] = fmaf(bc, accA[m][n][j], cc2 * accB[m][n][j]);
    __syncthreads();
#pragma unroll
    for (int m = 0; m < 2; ++m)
#pragma unroll
      for (int n = 0; n < 2; ++n)
#pragma unroll
        for (int j = 0; j < 4; ++j) {
          int row = ww * 32 + m * 16 + frow + j;
          int col = wv * 32 + n * 16 + fcol;
          float v = accB[m][n][j];
          unsigned short hi = f2bf(v);
          st_sw(QH, row, col, hi);
          st_sw(QL, row, col, f2bf(v - bf2f(hi)));
        }
    unsigned short th[16], tl[16];
#pragma unroll
    for (int r = 0; r < 16; ++r) {
      int idx = tid + r * 1024;
      int rr = idx >> 7, ccx = idx & 127;
      th[r] = ld_sw1(PH, rr, ccx);
      tl[r] = ld_sw1(PL, rr, ccx);
    }
    __syncthreads();
#pragma unroll
    for (int r = 0; r < 16; ++r) {
      int idx = tid + r * 1024;
      int rr = idx >> 7, ccx = idx & 127;
      st_sw(PH, ccx, rr, th[r]);
      st_sw(PL, ccx, rr, tl[r]);
    }
    __syncthreads();

    f32x4 accC[2][2];
#pragma unroll
    for (int m = 0; m < 2; ++m)
#pragma unroll
      for (int n = 0; n < 2; ++n) accC[m][n] = {};
#pragma unroll
    for (int kk = 0; kk < 128; kk += 32) {
      bf16x8 ah[2], al[2], bh[2], bl[2];
#pragma unroll
      for (int m = 0; m < 2; ++m) {
        ah[m] = ld_sw(PH, ww * 32 + m * 16 + lrow, kk + lk8);
        al[m] = ld_sw(PL, ww * 32 + m * 16 + lrow, kk + lk8);
      }
#pragma unroll
      for (int n = 0; n < 2; ++n) {
        bh[n] = ld_sw(QH, wv * 32 + n * 16 + lrow, kk + lk8);
        bl[n] = ld_sw(QL, wv * 32 + n * 16 + lrow, kk + lk8);
      }
#pragma unroll
      for (int m = 0; m < 2; ++m)
#pragma unroll
        for (int n = 0; n < 2; ++n) {
          accC[m][n] = __builtin_amdgcn_mfma_f32_16x16x32_bf16(ah[m], bh[n], accC[m][n], 0, 0, 0);
          accC[m][n] = __builtin_amdgcn_mfma_f32_16x16x32_bf16(ah[m], bl[n], accC[m][n], 0, 0, 0);
          accC[m][n] = __builtin_amdgcn_mfma_f32_16x16x32_bf16(al[m], bh[n], accC[m][n], 0, 0, 0);
        }
    }
#pragma unroll
    for (int m = 0; m < 2; ++m)
#pragma unroll
      for (int n = 0; n < 2; ++n)
#pragma unroll
        for (int j = 0; j < 4; ++j) {
          int row = ww * 32 + m * 16 + frow + j;
          int col = wv * 32 + n * 16 + fcol;
          float yv = bf2f(ld_sw1(PH, row, col)) + bf2f(ld_sw1(PL, row, col));
          accC[m][n][j] = fmaf(ac, yv, accC[m][n][j]);
        }
    __syncthreads();
#pragma unroll
    for (int m = 0; m < 2; ++m)
#pragma unroll
      for (int n = 0; n < 2; ++n)
#pragma unroll
        for (int j = 0; j < 4; ++j) {
          int row = ww * 32 + m * 16 + frow + j;
          int col = wv * 32 + n * 16 + fcol;
          float v = accC[m][n][j];
          unsigned short hi = f2bf(v);
          st_sw(PH, row, col, hi);
          st_sw(PL, row, col, f2bf(v - bf2f(hi)));
        }
    __syncthreads();
  }

  // fused apply: dw = (z==1 ? P : P^T); w += dw; renorm rows; maintain W1T.
  const int hh2 = tid >> 7, cc = tid & 127;
  float wnew[16];
#pragma unroll
  for (int r = 0; r < 16; ++r) {
    int rr = r * 8 + hh2;
    float dv = (z == 1) ? bf2f(ld_sw1(PH, rr, cc)) + bf2f(ld_sw1(PL, rr, cc))
                        : bf2f(ld_sw1(PH, cc, rr)) + bf2f(ld_sw1(PL, cc, rr));
    float wv = WW[(size_t)(zg * 128 + rr) * 128 + cc] + dv;
    wnew[r] = wv;
    float p = wave_sum64(wv * wv);
    if (l == 0) red[w * 16 + r] = p;
  }
  __syncthreads();
#pragma unroll
  for (int r = 0; r < 16; ++r) {
    int rr = r * 8 + hh2;
    float tot2 = red[w * 16 + r] + red[(w ^ 1) * 16 + r];
    float fsc = WN0[zg * 128 + rr] / (sqrtf(tot2) + 1e-5f);
    float wv = wnew[r] * fsc;
    WW[(size_t)(zg * 128 + rr) * 128 + cc] = wv;
    if (z == 1) {
      int g = zg & 15;
      W1T[((size_t)g * 128 + cc) * 128 + rr] = wv;
    }
  }
}

// ---------------------------------------------------------------- final projection (bf16 MFMA, BK=64 core)

__global__ __launch_bounds__(256) void k_final_mfma(const unsigned short* __restrict__ U,
                                                    const unsigned short* __restrict__ Wot,
                                                    float* __restrict__ out) {
  __shared__ __align__(16) char Al[16384];
  __shared__ __align__(16) char Bl[16384];
  f32x4 acc[4][4];
#pragma unroll
  for (int m = 0; m < 4; ++m)
#pragma unroll
    for (int n = 0; n < 4; ++n) acc[m][n] = {};

  const int row0 = blockIdx.x * 128, col0 = blockIdx.y * 128;
  gemm_core64(U, Wot, DMODEL, DMODEL, DMODEL, row0, col0, Al, Bl, acc);

  const int tid = threadIdx.x, w = tid >> 6, l = tid & 63;
  const int wr = (w >> 1) * 64, wc = (w & 1) * 64;
#pragma unroll
  for (int m = 0; m < 4; ++m)
#pragma unroll
    for (int j = 0; j < 4; ++j) {
      int t = row0 + wr + m * 16 + (l >> 4) * 4 + j;
      float* orow = out + (size_t)t * DMODEL + col0;
#pragma unroll
      for (int n = 0; n < 4; ++n)
        orow[wc + n * 16 + (l & 15)] = acc[m][n][j];
    }
}

// ---------------------------------------------------------------- launch

extern "C" void kernel_launch(void* const* d_in, const int* in_sizes, int n_in,
                              void* d_out, int out_size, void* d_ws, size_t ws_size,
                              hipStream_t stream) {
  (void)in_sizes; (void)n_in; (void)out_size;
  const float* x    = (const float*)d_in[0];
  const float* Wqkv = (const float*)d_in[1];
  const float* Wlr  = (const float*)d_in[2];
  const float* Wo   = (const float*)d_in[3];
  const float* Wsc  = (const float*)d_in[6];
  const float* bs   = (const float*)d_in[7];
  const float* lng  = (const float*)d_in[8];
  const float* lnb  = (const float*)d_in[9];
  const float* w0   = (const float*)d_in[10];
  const float* w1   = (const float*)d_in[11];
  const float* w2   = (const float*)d_in[12];

  float* Q = (float*)d_out;  // last read (k_out2 chunk 3) precedes k_final's write

  float* ws = (float*)d_ws;
  size_t off = 0;
  auto alloc = [&](size_t n) { float* p = ws + off; off += n; return p; };
  float* Km   = alloc((size_t)NH * LSEQ * HD);
  float* V    = alloc((size_t)NH * LSEQ * HD);
  float* Uf   = alloc((size_t)LSEQ * DMODEL / 2);   // U stored as bf16
  float* LR   = alloc((size_t)3 * NH * LSEQ);
  float* SCL  = alloc((size_t)NH * LSEQ);
  float* WW   = alloc((size_t)3 * NH * HD * HD);
  float* WN0  = alloc((size_t)3 * NH * HD);
  float* W1T  = alloc((size_t)NH * HD * HD);
  float* BUF  = alloc((size_t)3 * NH * HD * CH);    // chunk loop scratch
  float* DWP  = alloc((size_t)3 * NH * 8 * HD * HD);
  if (off * sizeof(float) > ws_size) return;        // clean failure instead of OOB

  unsigned short* U = (unsigned short*)Uf;
  unsigned short* xb  = (unsigned short*)BUF;                                   // pre-qkv
  unsigned short* Wqt = (unsigned short*)(BUF + (size_t)LSEQ * DMODEL / 2);
  float* Plr = BUF;                                                             // lrms partials
  unsigned short* Wot = (unsigned short*)BUF;                                   // post-loop

  k_init_w<<<3 * NH * HD, 64, 0, stream>>>(w0, w1, w2, WW, WN0, W1T);
  k_cast<<<2048, 256, 0, stream>>>(x, xb, LSEQ * DMODEL / 4);
  k_tcast<<<dim3(3 * DMODEL / 64, DMODEL / 64), 256, 0, stream>>>(Wqkv, Wqt, DMODEL, 3 * DMODEL);
  k_qkv_mfma<<<dim3(LSEQ / 128, 48), 256, 0, stream>>>(xb, Wqt, Q, Km, V);
  k_lrms5<<<dim3(LSEQ / 64, 16), 256, 0, stream>>>(x, Wlr, Wsc, Plr);
  k_lrsum<<<LSEQ * 64 / 256, 256, 0, stream>>>(Plr, bs, LR, SCL);

  for (int c = 0; c < 4; ++c) {
    int s = c * CH;
    k_out2<<<dim3(CH / 64, NH), 256, 0, stream>>>(WW, Q, SCL, lng, lnb, U, s);
    if (c < 3) {
      k_fe<<<dim3(CH / 128, NH), 1024, 0, stream>>>(WW, W1T, Km, V, BUF, s);
      k_dwp_mx<<<dim3(8, NH, 3), 256, 0, stream>>>(BUF, Km, V, LR, DWP, s);
      k_ns5_mfma<<<3 * NH, 1024, 0, stream>>>(DWP, WW, WN0, W1T);
    }
  }
  k_tcast<<<dim3(DMODEL / 64, DMODEL / 64), 256, 0, stream>>>(Wo, Wot, DMODEL, DMODEL);
  k_final_mfma<<<dim3(LSEQ / 128, DMODEL / 128), 256, 0, stream>>>(U, Wot, (float*)d_out);
}

// Round 13
// 1302.340 us; speedup vs baseline: 1.0112x; 1.0112x over previous
//
#include <hip/hip_runtime.h>
#include <hip/hip_bf16.h>
#include <cstdint>
#include <cstddef>

#define LSEQ   8192
#define DMODEL 2048
#define NH     16      // heads == groups
#define HD     128     // head dim == hidden dim
#define CH     2048    // chunk length (group-space positions)

typedef __attribute__((ext_vector_type(8))) __bf16 bf16x8;
typedef __attribute__((ext_vector_type(4))) float f32x4;

// ---------------------------------------------------------------- helpers

__device__ __forceinline__ float wave_sum64(float v) {
#pragma unroll
  for (int m = 32; m; m >>= 1) v += __shfl_xor(v, m, 64);
  return v;
}

__device__ __forceinline__ float sigm(float x) { return 1.0f / (1.0f + expf(-x)); }

// RTNE float -> bf16 bits
__device__ __forceinline__ unsigned short f2bf(float f) {
  unsigned int u = __float_as_uint(f);
  u += 0x7FFFu + ((u >> 16) & 1u);
  return (unsigned short)(u >> 16);
}
__device__ __forceinline__ float bf2f(unsigned short h) {
  return __uint_as_float((unsigned int)h << 16);
}

// async global->LDS, 16B per lane.
__device__ __forceinline__ void gload_lds16(const void* g, void* l) {
  __builtin_amdgcn_global_load_lds((__attribute__((address_space(1))) void*)(g),
                                   (__attribute__((address_space(3))) void*)(l), 16, 0, 0);
}

union bfu8 { bf16x8 v; unsigned short u[8]; };

// ---------------------------------------------------------------- casts

__global__ void k_cast(const float* __restrict__ X, unsigned short* __restrict__ Xb, int n4) {
  int i = blockIdx.x * 256 + threadIdx.x;
  int stride = gridDim.x * 256;
  for (; i < n4; i += stride) {
    float4 v = ((const float4*)X)[i];
    ushort4 o;
    o.x = f2bf(v.x); o.y = f2bf(v.y); o.z = f2bf(v.z); o.w = f2bf(v.w);
    ((ushort4*)Xb)[i] = o;
  }
}

// W (K x N, fp32) -> Wt (N x K, bf16). grid (N/64, K/64), block 256.
__global__ void k_tcast(const float* __restrict__ W, unsigned short* __restrict__ Wt,
                        int K, int N) {
  __shared__ float t[64][65];
  const int n0 = blockIdx.x * 64, k0 = blockIdx.y * 64;
  const int tid = threadIdx.x;
  const int cx = tid & 63, ry = tid >> 6;
#pragma unroll
  for (int r = 0; r < 16; ++r) {
    int row = ry + r * 4;
    t[row][cx] = W[(size_t)(k0 + row) * N + n0 + cx];
  }
  __syncthreads();
#pragma unroll
  for (int r = 0; r < 16; ++r) {
    int nn = ry + r * 4;
    Wt[(size_t)(n0 + nn) * K + k0 + cx] = f2bf(t[cx][nn]);
  }
}

// ---------------------------------------------------------------- bf16 MFMA GEMM core (m97 style)

__device__ __forceinline__ void gemm_core(const unsigned short* __restrict__ A,
                                          const unsigned short* __restrict__ B,
                                          int K, int ldA, int ldB, int row0, int col0,
                                          unsigned short* Al, unsigned short* Bl,
                                          f32x4 acc[4][4]) {
  const int tid = threadIdx.x;
  const int w = tid >> 6, l = tid & 63;
  const int lrow = l & 15, lk = (l >> 4) * 8;
  const int wr = (w >> 1) * 64, wc = (w & 1) * 64;
  const int srow = l >> 2, skk = (l & 3) * 8;

  for (int kk = 0; kk < K; kk += 32) {
#pragma unroll
    for (int q = 0; q < 2; ++q) {
      int c = w * 2 + q;
      gload_lds16(A + (size_t)(row0 + c * 16 + srow) * ldA + kk + skk, &Al[c * 512]);
      gload_lds16(B + (size_t)(col0 + c * 16 + srow) * ldB + kk + skk, &Bl[c * 512]);
    }
    __syncthreads();
    bf16x8 af[4], bfr[4];
#pragma unroll
    for (int m = 0; m < 4; ++m)
      af[m] = *(const bf16x8*)&Al[(wr + m * 16 + lrow) * 32 + lk];
#pragma unroll
    for (int n = 0; n < 4; ++n)
      bfr[n] = *(const bf16x8*)&Bl[(wc + n * 16 + lrow) * 32 + lk];
#pragma unroll
    for (int m = 0; m < 4; ++m)
#pragma unroll
      for (int n = 0; n < 4; ++n)
        acc[m][n] = __builtin_amdgcn_mfma_f32_16x16x32_bf16(af[m], bfr[n], acc[m][n], 0, 0, 0);
    __syncthreads();
  }
}

// ---------------------------------------------------------------- swizzled LDS helpers (bf16, 128-col rows)

__device__ __forceinline__ bf16x8 ld_sw(const unsigned short* base, int row, int kcol) {
  int byte = (row * 256 + kcol * 2) ^ ((row & 7) << 4);
  return *(const bf16x8*)((const char*)base + byte);
}
__device__ __forceinline__ void st_sw(unsigned short* base, int row, int col, unsigned short v) {
  int byte = (row * 256 + col * 2) ^ ((row & 7) << 4);
  *(unsigned short*)((char*)base + byte) = v;
}
__device__ __forceinline__ unsigned short ld_sw1(const unsigned short* base, int row, int col) {
  int byte = (row * 256 + col * 2) ^ ((row & 7) << 4);
  return *(const unsigned short*)((const char*)base + byte);
}

__device__ __forceinline__ void stage_sw(const float* __restrict__ src, int ld,
                                         unsigned short* dst, int tid) {
#pragma unroll
  for (int p = 0; p < 16; ++p) {
    int row = p * 8 + (tid >> 5);
    int col = (tid & 31) * 4;
    float4 v = *(const float4*)(src + (size_t)row * ld + col);
    int byte = (row * 256 + col * 2) ^ ((row & 7) << 4);
    unsigned short* d = (unsigned short*)((char*)dst + byte);
    d[0] = f2bf(v.x); d[1] = f2bf(v.y); d[2] = f2bf(v.z); d[3] = f2bf(v.w);
  }
}

__device__ __forceinline__ void stage_sw64(const float* __restrict__ src, int ld,
                                           unsigned short* dst, int tid) {
#pragma unroll
  for (int p = 0; p < 8; ++p) {
    int row = p * 8 + (tid >> 5);
    int col = (tid & 31) * 4;
    float4 v = *(const float4*)(src + (size_t)row * ld + col);
    int byte = (row * 256 + col * 2) ^ ((row & 7) << 4);
    unsigned short* d = (unsigned short*)((char*)dst + byte);
    d[0] = f2bf(v.x); d[1] = f2bf(v.y); d[2] = f2bf(v.z); d[3] = f2bf(v.w);
  }
}

__device__ __forceinline__ void stage_hl(const float* __restrict__ src, int ld,
                                         unsigned short* H, unsigned short* L, int tid) {
#pragma unroll
  for (int p = 0; p < 16; ++p) {
    int row = p * 8 + (tid >> 5);
    int col = (tid & 31) * 4;
    float4 v = *(const float4*)(src + (size_t)row * ld + col);
    int byte = (row * 256 + col * 2) ^ ((row & 7) << 4);
    unsigned short* h = (unsigned short*)((char*)H + byte);
    unsigned short* l = (unsigned short*)((char*)L + byte);
    const float* pv = (const float*)&v;
#pragma unroll
    for (int i = 0; i < 4; ++i) {
      unsigned short hi = f2bf(pv[i]);
      h[i] = hi;
      l[i] = f2bf(pv[i] - bf2f(hi));
    }
  }
}

__device__ __forceinline__ void stage_hl_1024(const float* __restrict__ src, int ld,
                                              unsigned short* H, unsigned short* L, int tid) {
#pragma unroll
  for (int p = 0; p < 4; ++p) {
    int row = p * 32 + (tid >> 5);
    int col = (tid & 31) * 4;
    float4 v = *(const float4*)(src + (size_t)row * ld + col);
    int byte = (row * 256 + col * 2) ^ ((row & 7) << 4);
    unsigned short* h = (unsigned short*)((char*)H + byte);
    unsigned short* l = (unsigned short*)((char*)L + byte);
    const float* pv = (const float*)&v;
#pragma unroll
    for (int i = 0; i < 4; ++i) {
      unsigned short hi = f2bf(pv[i]);
      h[i] = hi;
      l[i] = f2bf(pv[i] - bf2f(hi));
    }
  }
}

__device__ __forceinline__ void stage_hl_ts(const float* __restrict__ src, int ld,
                                            const float* __restrict__ lr,
                                            unsigned short* H, unsigned short* L, int tid) {
#pragma unroll
  for (int p = 0; p < 16; ++p) {
    int t = p * 8 + (tid >> 5);
    int d = (tid & 31) * 4;
    float4 v = *(const float4*)(src + (size_t)t * ld + d);
    float sc = lr[t];
    const float* pv = (const float*)&v;
#pragma unroll
    for (int i = 0; i < 4; ++i) {
      float x = pv[i] * sc;
      unsigned short hi = f2bf(x);
      st_sw(H, d + i, t, hi);
      st_sw(L, d + i, t, f2bf(x - bf2f(hi)));
    }
  }
}

// ---------------------------------------------------------------- init w + row norms (+ w1^T copy)

__global__ void k_init_w(const float* __restrict__ w0, const float* __restrict__ w1,
                         const float* __restrict__ w2, float* __restrict__ WW,
                         float* __restrict__ WN0, float* __restrict__ W1T) {
  int rid = blockIdx.x;
  int m = rid >> 11;
  int gr = rid & 2047;
  const float* src = (m == 0) ? w0 : (m == 1) ? w1 : w2;
  const float* row = src + (size_t)gr * HD;
  float* drow = WW + ((size_t)m * 2048 + gr) * HD;
  int l = threadIdx.x;
  float v0 = row[l], v1 = row[l + 64];
  drow[l] = v0; drow[l + 64] = v1;
  if (m == 1) {
    int g = gr >> 7, r = gr & 127;
    W1T[((size_t)g * 128 + l) * 128 + r] = v0;
    W1T[((size_t)g * 128 + l + 64) * 128 + r] = v1;
  }
  float s = wave_sum64(v0 * v0 + v1 * v1);
  if (l == 0) WN0[rid] = sqrtf(s);
}

// ---------------------------------------------------------------- qkv projection (bf16 MFMA + fused silu/l2norm)
// m97 structure, natural 2D grid (64, 48). 283us / MfmaUtil 33.5% (R9/R11).

__global__ __launch_bounds__(256) void k_qkv_mfma(const unsigned short* __restrict__ xb,
                                                  const unsigned short* __restrict__ Wqt,
                                                  float* __restrict__ Q, float* __restrict__ Km,
                                                  float* __restrict__ V) {
  __shared__ unsigned short Al[128 * 32];
  __shared__ unsigned short Bl[128 * 32];
  __shared__ float nrm[128][2];
  const int bx = blockIdx.x, ct = blockIdx.y;

  f32x4 acc[4][4];
#pragma unroll
  for (int m = 0; m < 4; ++m)
#pragma unroll
    for (int n = 0; n < 4; ++n) acc[m][n] = {};

  gemm_core(xb, Wqt, DMODEL, DMODEL, DMODEL, bx * 128, ct * 128, Al, Bl, acc);

  const int hh = ct / 3, which = ct % 3;
  float* dst = (which == 0) ? Q : (which == 1) ? Km : V;
  const int tid = threadIdx.x, w = tid >> 6, l = tid & 63;
  const int wr = (w >> 1) * 64, wc = (w & 1) * 64;

#pragma unroll
  for (int m = 0; m < 4; ++m)
#pragma unroll
    for (int n = 0; n < 4; ++n)
#pragma unroll
      for (int j = 0; j < 4; ++j) {
        float v = acc[m][n][j];
        acc[m][n][j] = v * sigm(v);
      }

  float f[4][4];
  if (which != 2) {
#pragma unroll
    for (int m = 0; m < 4; ++m)
#pragma unroll
      for (int j = 0; j < 4; ++j) {
        float p = 0.0f;
#pragma unroll
        for (int n = 0; n < 4; ++n) p = fmaf(acc[m][n][j], acc[m][n][j], p);
        p += __shfl_xor(p, 1, 64);
        p += __shfl_xor(p, 2, 64);
        p += __shfl_xor(p, 4, 64);
        p += __shfl_xor(p, 8, 64);
        f[m][j] = p;
      }
    if ((l & 15) == 0) {
#pragma unroll
      for (int m = 0; m < 4; ++m)
#pragma unroll
        for (int j = 0; j < 4; ++j)
          nrm[wr + m * 16 + (l >> 4) * 4 + j][w & 1] = f[m][j];
    }
    __syncthreads();
#pragma unroll
    for (int m = 0; m < 4; ++m)
#pragma unroll
      for (int j = 0; j < 4; ++j) {
        int row = wr + m * 16 + (l >> 4) * 4 + j;
        f[m][j] = 1.0f / (sqrtf(nrm[row][0] + nrm[row][1]) + 1e-5f);
      }
  } else {
#pragma unroll
    for (int m = 0; m < 4; ++m)
#pragma unroll
      for (int j = 0; j < 4; ++j) f[m][j] = 1.0f;
  }

#pragma unroll
  for (int m = 0; m < 4; ++m)
#pragma unroll
    for (int j = 0; j < 4; ++j) {
      int t = bx * 128 + wr + m * 16 + (l >> 4) * 4 + j;
      int fth = t * NH + hh;
      int g = fth >> 13, tp = fth & 8191;
      float* drow = dst + ((size_t)g * LSEQ + tp) * HD;
#pragma unroll
      for (int n = 0; n < 4; ++n)
        drow[wc + n * 16 + (l & 15)] = acc[m][n][j] * f[m][j];
    }
}

// ---------------------------------------------------------------- lr / scale: K-split GEMM + reduce

__global__ __launch_bounds__(256) void k_lrms5(const float* __restrict__ x,
                                               const float* __restrict__ Wlr,
                                               const float* __restrict__ Wsc,
                                               float* __restrict__ P) {
  __shared__ float Xs[128][67];
  __shared__ float Ws[128][68];
  const int tb = blockIdx.x;
  const int kp = blockIdx.y;
  const int tid = threadIdx.x;
  for (int i = tid; i < 128 * 64; i += 256) {
    int k = i >> 6, c = i & 63;
    float wv = (c < 48) ? Wlr[(size_t)(kp * 128 + k) * 48 + c]
                        : Wsc[(size_t)(kp * 128 + k) * 16 + (c - 48)];
    Ws[k][c] = wv;
  }
  const int t8 = tid >> 5, kk = tid & 31;
#pragma unroll
  for (int r = 0; r < 8; ++r) {
    int t = t8 + r * 8;
    float4 v = *(const float4*)(x + (size_t)(tb * 64 + t) * DMODEL + kp * 128 + kk * 4);
    Xs[kk * 4 + 0][t] = v.x; Xs[kk * 4 + 1][t] = v.y;
    Xs[kk * 4 + 2][t] = v.z; Xs[kk * 4 + 3][t] = v.w;
  }
  __syncthreads();
  const int ty = tid >> 4, tx = tid & 15;
  float acc[4][4];
#pragma unroll
  for (int i = 0; i < 4; ++i)
#pragma unroll
    for (int j = 0; j < 4; ++j) acc[i][j] = 0.0f;
  for (int k = 0; k < 128; ++k) {
    float a[4], b[4];
#pragma unroll
    for (int i = 0; i < 4; ++i) a[i] = Xs[k][ty * 4 + i];
#pragma unroll
    for (int j = 0; j < 4; ++j) b[j] = Ws[k][tx * 4 + j];
#pragma unroll
    for (int i = 0; i < 4; ++i)
#pragma unroll
      for (int j = 0; j < 4; ++j) acc[i][j] = fmaf(a[i], b[j], acc[i][j]);
  }
  float* o = P + ((size_t)tb * 16 + kp) * 4096;
#pragma unroll
  for (int i = 0; i < 4; ++i)
#pragma unroll
    for (int j = 0; j < 4; ++j)
      o[(ty * 4 + i) * 64 + tx * 4 + j] = acc[i][j];
}

__global__ void k_lrsum(const float* __restrict__ P, const float* __restrict__ bs,
                        float* __restrict__ LR, float* __restrict__ SCL) {
  int e = blockIdx.x * 256 + threadIdx.x;
  int t = e >> 6, c = e & 63;
  const float* base = P + ((size_t)(t >> 6) * 16) * 4096 + (t & 63) * 64 + c;
  float sum = 0.0f;
#pragma unroll
  for (int kp = 0; kp < 16; ++kp) sum += base[(size_t)kp * 4096];
  if (c < 48) {
    float base_lr_inv = 0.01f + logf(-expm1f(-0.01f));
    float v = sum + base_lr_inv;
    float sp = fmaxf(v, 0.0f) + log1pf(expf(-fabsf(v)));
    LR[(size_t)c * LSEQ + t] = sp;
  } else {
    float v = sum + bs[c - 48];
    SCL[(size_t)(c - 48) * LSEQ + t] = v * sigm(v);
  }
}

// ---------------------------------------------------------------- per-chunk output (bf16 MFMA + fused LN/scale)
// 64-token tiles, 80 KB LDS -> 2 blocks/CU.

__global__ __launch_bounds__(256) void k_out2(const float* __restrict__ WW,
                                              const float* __restrict__ Q,
                                              const float* __restrict__ SCL,
                                              const float* __restrict__ lng,
                                              const float* __restrict__ lnb,
                                              unsigned short* __restrict__ U, int s) {
  __shared__ __align__(16) char smem[81920];
  unsigned short* Qs  = (unsigned short*)smem;
  unsigned short* W0s = (unsigned short*)(smem + 16384);
  unsigned short* W2s = (unsigned short*)(smem + 49152);
  float* Os = (float*)(smem + 16384);

  const int g = blockIdx.y;
  const int t0 = blockIdx.x * 64;
  const int tid = threadIdx.x;
  const int w = tid >> 6, l = tid & 63;
  const int lrow = l & 15, lk8 = (l >> 4) * 8;
  const int wr = (w >> 1) * 32, wc = (w & 1) * 64;

  const float* Qg  = Q + ((size_t)g * LSEQ + s + t0) * HD;
  const float* w0g = WW + ((size_t)0 * 2048 + g * 128) * 128;
  const float* w1g = WW + ((size_t)1 * 2048 + g * 128) * 128;
  const float* w2g = WW + ((size_t)2 * 2048 + g * 128) * 128;

  stage_sw64(Qg, HD, Qs, tid);
  stage_sw(w0g, 128, W0s, tid);
  stage_sw(w2g, 128, W2s, tid);
  __syncthreads();

  f32x4 ga[2][4], ha[2][4];
#pragma unroll
  for (int m = 0; m < 2; ++m)
#pragma unroll
    for (int n = 0; n < 4; ++n) { ga[m][n] = {}; ha[m][n] = {}; }
#pragma unroll
  for (int kk = 0; kk < 128; kk += 32) {
    bf16x8 af[2], b0[4], b2[4];
#pragma unroll
    for (int m = 0; m < 2; ++m) af[m] = ld_sw(Qs, wr + m * 16 + lrow, kk + lk8);
#pragma unroll
    for (int n = 0; n < 4; ++n) {
      b0[n] = ld_sw(W0s, wc + n * 16 + lrow, kk + lk8);
      b2[n] = ld_sw(W2s, wc + n * 16 + lrow, kk + lk8);
    }
#pragma unroll
    for (int m = 0; m < 2; ++m)
#pragma unroll
      for (int n = 0; n < 4; ++n) {
        ga[m][n] = __builtin_amdgcn_mfma_f32_16x16x32_bf16(af[m], b0[n], ga[m][n], 0, 0, 0);
        ha[m][n] = __builtin_amdgcn_mfma_f32_16x16x32_bf16(af[m], b2[n], ha[m][n], 0, 0, 0);
      }
  }
  __syncthreads();
#pragma unroll
  for (int m = 0; m < 2; ++m)
#pragma unroll
    for (int n = 0; n < 4; ++n)
#pragma unroll
      for (int j = 0; j < 4; ++j) {
        int row = wr + m * 16 + (l >> 4) * 4 + j;
        int col = wc + n * 16 + (l & 15);
        float gv = ga[m][n][j];
        st_sw(Qs, row, col, f2bf(gv * sigm(gv) * ha[m][n][j]));
      }
  stage_sw(w1g, 128, W0s, tid);
  __syncthreads();

  f32x4 oa[2][4];
#pragma unroll
  for (int m = 0; m < 2; ++m)
#pragma unroll
    for (int n = 0; n < 4; ++n) oa[m][n] = {};
#pragma unroll
  for (int kk = 0; kk < 128; kk += 32) {
    bf16x8 af[2], b1[4];
#pragma unroll
    for (int m = 0; m < 2; ++m) af[m] = ld_sw(Qs, wr + m * 16 + lrow, kk + lk8);
#pragma unroll
    for (int n = 0; n < 4; ++n) b1[n] = ld_sw(W0s, wc + n * 16 + lrow, kk + lk8);
#pragma unroll
    for (int m = 0; m < 2; ++m)
#pragma unroll
      for (int n = 0; n < 4; ++n)
        oa[m][n] = __builtin_amdgcn_mfma_f32_16x16x32_bf16(af[m], b1[n], oa[m][n], 0, 0, 0);
  }
  __syncthreads();
#pragma unroll
  for (int m = 0; m < 2; ++m)
#pragma unroll
    for (int n = 0; n < 4; ++n)
#pragma unroll
      for (int j = 0; j < 4; ++j) {
        int row = wr + m * 16 + (l >> 4) * 4 + j;
        int col = wc + n * 16 + (l & 15);
        Os[row * 132 + col] = oa[m][n][j];
      }
  __syncthreads();

  const int tok = tid >> 2, part = tid & 3;
  const float* orow = Os + tok * 132 + part * 32;
  float sum = 0.0f;
#pragma unroll
  for (int q = 0; q < 8; ++q) {
    float4 v = *(const float4*)(orow + q * 4);
    sum += (v.x + v.y) + (v.z + v.w);
  }
  sum += __shfl_xor(sum, 1, 64);
  sum += __shfl_xor(sum, 2, 64);
  float mu = sum * (1.0f / 128.0f);
  float vs = 0.0f;
#pragma unroll
  for (int q = 0; q < 8; ++q) {
    float4 v = *(const float4*)(orow + q * 4);
    float d0 = v.x - mu, d1 = v.y - mu, d2 = v.z - mu, d3 = v.w - mu;
    vs += d0 * d0 + d1 * d1 + d2 * d2 + d3 * d3;
  }
  vs += __shfl_xor(vs, 1, 64);
  vs += __shfl_xor(vs, 2, 64);
  float rstd = rsqrtf(vs * (1.0f / 128.0f) + 1e-6f);
  int tabs = s + t0 + tok;
  float sc = SCL[(size_t)g * LSEQ + tabs];
  unsigned short* urow = U + (size_t)tabs * DMODEL + g * HD + part * 32;
#pragma unroll
  for (int q = 0; q < 8; ++q) {
    float4 v = *(const float4*)(orow + q * 4);
    int d = part * 32 + q * 4;
    ushort4 o;
    o.x = f2bf(((v.x - mu) * rstd * lng[d + 0] + lnb[d + 0]) * sc);
    o.y = f2bf(((v.y - mu) * rstd * lng[d + 1] + lnb[d + 1]) * sc);
    o.z = f2bf(((v.z - mu) * rstd * lng[d + 2] + lnb[d + 2]) * sc);
    o.w = f2bf(((v.w - mu) * rstd * lng[d + 3] + lnb[d + 3]) * sc);
    *(ushort4*)(urow + q * 4) = o;
  }
}

// ---------------------------------------------------------------- fused front GEMMs + elementwise

__global__ __launch_bounds__(1024) void k_fe(const float* __restrict__ WW,
                                             const float* __restrict__ W1T,
                                             const float* __restrict__ Km,
                                             const float* __restrict__ V,
                                             float* __restrict__ BUF, int s) {
  __shared__ __align__(16) char smem[131072];
  unsigned short* KH = (unsigned short*)smem;
  unsigned short* KL = (unsigned short*)(smem + 32768);
  unsigned short* VH = (unsigned short*)(smem + 65536);
  unsigned short* VL = (unsigned short*)(smem + 98304);

  const int tt0 = blockIdx.x * 128;
  const int g = blockIdx.y;
  const int tid = threadIdx.x;
  const int w = tid >> 6, l = tid & 63;
  const int ww = w >> 2, wv = w & 3;
  const int lrow = l & 15, lk8 = (l >> 4) * 8;
  const int frow = (l >> 4) * 4, fcol = l & 15;

  stage_hl_1024(Km + ((size_t)g * LSEQ + s + tt0) * HD, HD, KH, KL, tid);
  stage_hl_1024(V + ((size_t)g * LSEQ + s + tt0) * HD, HD, VH, VL, tid);
  __syncthreads();

  const float* Asrc[3];
  Asrc[0] = WW + ((size_t)0 * 2048 + g * 128) * 128;
  Asrc[1] = WW + ((size_t)2 * 2048 + g * 128) * 128;
  Asrc[2] = W1T + (size_t)g * 16384;

  f32x4 acc[3][2][2];
#pragma unroll
  for (int q = 0; q < 3; ++q)
#pragma unroll
    for (int m = 0; m < 2; ++m)
#pragma unroll
      for (int n = 0; n < 2; ++n) acc[q][m][n] = {};

#pragma unroll 1
  for (int q = 0; q < 3; ++q) {
    const float* src = Asrc[q];
    const unsigned short* BH = (q == 2) ? VH : KH;
    const unsigned short* BL = (q == 2) ? VL : KL;
#pragma unroll
    for (int kk = 0; kk < 128; kk += 32) {
      bf16x8 ah[2], al[2], bh[2], bl[2];
#pragma unroll
      for (int m = 0; m < 2; ++m) {
        int row = ww * 32 + m * 16 + lrow;
        float4 v0 = *(const float4*)(src + (size_t)row * 128 + kk + lk8);
        float4 v1 = *(const float4*)(src + (size_t)row * 128 + kk + lk8 + 4);
        bfu8 h, lo;
        const float* p0 = (const float*)&v0;
        const float* p1 = (const float*)&v1;
#pragma unroll
        for (int i = 0; i < 4; ++i) {
          unsigned short hb0 = f2bf(p0[i]);
          h.u[i] = hb0; lo.u[i] = f2bf(p0[i] - bf2f(hb0));
          unsigned short hb1 = f2bf(p1[i]);
          h.u[i + 4] = hb1; lo.u[i + 4] = f2bf(p1[i] - bf2f(hb1));
        }
        ah[m] = h.v; al[m] = lo.v;
      }
#pragma unroll
      for (int n = 0; n < 2; ++n) {
        int row = wv * 32 + n * 16 + lrow;
        bh[n] = ld_sw(BH, row, kk + lk8);
        bl[n] = ld_sw(BL, row, kk + lk8);
      }
#pragma unroll
      for (int m = 0; m < 2; ++m)
#pragma unroll
        for (int n = 0; n < 2; ++n) {
          acc[q][m][n] = __builtin_amdgcn_mfma_f32_16x16x32_bf16(ah[m], bh[n], acc[q][m][n], 0, 0, 0);
          acc[q][m][n] = __builtin_amdgcn_mfma_f32_16x16x32_bf16(ah[m], bl[n], acc[q][m][n], 0, 0, 0);
          acc[q][m][n] = __builtin_amdgcn_mfma_f32_16x16x32_bf16(al[m], bh[n], acc[q][m][n], 0, 0, 0);
        }
    }
  }

  float* out0 = BUF + (size_t)0 * (NH * 128 * CH) + (size_t)g * 128 * CH;
  float* out1 = BUF + (size_t)1 * (NH * 128 * CH) + (size_t)g * 128 * CH;
  float* out2 = BUF + (size_t)2 * (NH * 128 * CH) + (size_t)g * 128 * CH;
#pragma unroll
  for (int m = 0; m < 2; ++m)
#pragma unroll
    for (int n = 0; n < 2; ++n)
#pragma unroll
      for (int j = 0; j < 4; ++j) {
        int row = ww * 32 + m * 16 + frow + j;
        int col = wv * 32 + n * 16 + fcol;
        float gb = acc[0][m][n][j];
        float hb = acc[1][m][n][j];
        float dh = acc[2][m][n][j];
        float sg = sigm(gb);
        float sgb = gb * sg;
        float hid = sgb * hb;
        float dgate = dh * hb;
        float dgb = dgate * sg * (1.0f + gb * (1.0f - sg));
        float dhb = dh * sgb;
        size_t o = (size_t)row * CH + tt0 + col;
        out0[o] = hid; out1[o] = dgb; out2[o] = dhb;
      }
}

// partial dW GEMMs over 256-token slices (split-bf16). grid (8, NH, 3).
__global__ __launch_bounds__(256) void k_dwp_mx(const float* __restrict__ BUF,
                                                const float* __restrict__ Km,
                                                const float* __restrict__ V,
                                                const float* __restrict__ LR,
                                                float* __restrict__ DWP, int s) {
  __shared__ __align__(16) char smem[131072];
  unsigned short* AH = (unsigned short*)smem;
  unsigned short* AL = (unsigned short*)(smem + 32768);
  unsigned short* BH = (unsigned short*)(smem + 65536);
  unsigned short* BL = (unsigned short*)(smem + 98304);

  const int p = blockIdx.x;
  const int g = blockIdx.y;
  const int z = blockIdx.z;
  const int tid = threadIdx.x;
  const int w = tid >> 6, l = tid & 63;
  const int lrow = l & 15, lk8 = (l >> 4) * 8;
  const int wr = (w >> 1) * 64, wc = (w & 1) * 64;

  const int msel = (z == 0) ? 1 : (z == 1) ? 0 : 2;
  const float* M = BUF + (size_t)msel * (NH * 128 * CH) + (size_t)g * 128 * CH;
  const float* N = (z == 1) ? V : Km;
  const float* lr = LR + (size_t)(z * NH + g) * LSEQ;
  const int ts = p * 256;

  f32x4 acc[4][4];
#pragma unroll
  for (int m = 0; m < 4; ++m)
#pragma unroll
    for (int n = 0; n < 4; ++n) acc[m][n] = {};

  for (int h = 0; h < 2; ++h) {
    if (h) __syncthreads();
    stage_hl(M + ts + h * 128, CH, AH, AL, tid);
    stage_hl_ts(N + ((size_t)g * LSEQ + s + ts + h * 128) * HD, HD,
                lr + s + ts + h * 128, BH, BL, tid);
    __syncthreads();
#pragma unroll
    for (int kk = 0; kk < 128; kk += 32) {
      bf16x8 ah[4], al4[4], bh[4], bl4[4];
#pragma unroll
      for (int m = 0; m < 4; ++m) {
        ah[m] = ld_sw(AH, wr + m * 16 + lrow, kk + lk8);
        al4[m] = ld_sw(AL, wr + m * 16 + lrow, kk + lk8);
      }
#pragma unroll
      for (int n = 0; n < 4; ++n) {
        bh[n] = ld_sw(BH, wc + n * 16 + lrow, kk + lk8);
        bl4[n] = ld_sw(BL, wc + n * 16 + lrow, kk + lk8);
      }
#pragma unroll
      for (int m = 0; m < 4; ++m)
#pragma unroll
        for (int n = 0; n < 4; ++n) {
          acc[m][n] = __builtin_amdgcn_mfma_f32_16x16x32_bf16(ah[m], bh[n], acc[m][n], 0, 0, 0);
          acc[m][n] = __builtin_amdgcn_mfma_f32_16x16x32_bf16(ah[m], bl4[n], acc[m][n], 0, 0, 0);
          acc[m][n] = __builtin_amdgcn_mfma_f32_16x16x32_bf16(al4[m], bh[n], acc[m][n], 0, 0, 0);
        }
    }
  }

  float* outp = DWP + (((size_t)(z * NH + g)) * 8 + p) * 16384;
#pragma unroll
  for (int m = 0; m < 4; ++m)
#pragma unroll
    for (int n = 0; n < 4; ++n)
#pragma unroll
      for (int j = 0; j < 4; ++j) {
        int row = wr + m * 16 + (l >> 4) * 4 + j;
        int col = wc + n * 16 + (l & 15);
        outp[row * 128 + col] = acc[m][n][j];
      }
}

// ---------------------------------------------------------------- Newton-Schulz 5 + fused w-update
__global__ __launch_bounds__(1024) void k_ns5_mfma(const float* __restrict__ DWP,
                                                   float* __restrict__ WW,
                                                   const float* __restrict__ WN0,
                                                   float* __restrict__ W1T) {
  __shared__ __align__(16) char smem[131072];
  unsigned short* PH = (unsigned short*)smem;
  unsigned short* PL = (unsigned short*)(smem + 32768);
  unsigned short* QH = (unsigned short*)(smem + 65536);
  unsigned short* QL = (unsigned short*)(smem + 98304);
  float* red = (float*)(smem + 65536);

  const float NA[5] = {4.0848f, 3.9505f, 3.7418f, 2.8769f, 2.8366f};
  const float NB[5] = {-6.8946f, -6.3029f, -5.5913f, -3.1427f, -3.0525f};
  const float NC[5] = {2.927f, 2.6377f, 2.3037f, 1.2046f, 1.2012f};
  const int zg = blockIdx.x;
  const int z = zg >> 4;
  const float* base = DWP + (size_t)zg * 8 * 16384;
  const int tid = threadIdx.x;
  const int w = tid >> 6, l = tid & 63;
  const int ww = w >> 2, wv = w & 3;
  const int lrow = l & 15, lk8 = (l >> 4) * 8;
  const int frow = (l >> 4) * 4, fcol = l & 15;

  float vals[16];
  float psum = 0.0f;
#pragma unroll
  for (int r = 0; r < 16; ++r) {
    int idx = tid + r * 1024;
    float sv = 0.0f;
#pragma unroll
    for (int p = 0; p < 8; ++p) sv += base[(size_t)p * 16384 + idx];
    vals[r] = sv;
    psum = fmaf(sv, sv, psum);
  }
  psum = wave_sum64(psum);
  if (l == 0) red[w] = psum;
  __syncthreads();
  float tot = 0.0f;
#pragma unroll
  for (int i = 0; i < 16; ++i) tot += red[i];
  float scl = 1.0f / (sqrtf(tot) + 1e-7f);
  __syncthreads();
#pragma unroll
  for (int r = 0; r < 16; ++r) {
    int idx = tid + r * 1024;
    int rr = idx >> 7, cc = idx & 127;
    float v = vals[r] * scl;
    unsigned short hi = f2bf(v);
    st_sw(PH, rr, cc, hi);
    st_sw(PL, rr, cc, f2bf(v - bf2f(hi)));
  }
  __syncthreads();

#pragma unroll 1
  for (int it = 0; it < 5; ++it) {
    const float ac = NA[it], bc = NB[it], cc2 = NC[it];

    f32x4 accA[2][2];
#pragma unroll
    for (int m = 0; m < 2; ++m)
#pragma unroll
      for (int n = 0; n < 2; ++n) accA[m][n] = {};
#pragma unroll
    for (int kk = 0; kk < 128; kk += 32) {
      bf16x8 ah[2], al[2], bh[2], bl[2];
#pragma unroll
      for (int m = 0; m < 2; ++m) {
        ah[m] = ld_sw(PH, ww * 32 + m * 16 + lrow, kk + lk8);
        al[m] = ld_sw(PL, ww * 32 + m * 16 + lrow, kk + lk8);
      }
#pragma unroll
      for (int n = 0; n < 2; ++n) {
        bh[n] = ld_sw(PH, wv * 32 + n * 16 + lrow, kk + lk8);
        bl[n] = ld_sw(PL, wv * 32 + n * 16 + lrow, kk + lk8);
      }
#pragma unroll
      for (int m = 0; m < 2; ++m)
#pragma unroll
        for (int n = 0; n < 2; ++n) {
          accA[m][n] = __builtin_amdgcn_mfma_f32_16x16x32_bf16(ah[m], bh[n], accA[m][n], 0, 0, 0);
          accA[m][n] = __builtin_amdgcn_mfma_f32_16x16x32_bf16(ah[m], bl[n], accA[m][n], 0, 0, 0);
          accA[m][n] = __builtin_amdgcn_mfma_f32_16x16x32_bf16(al[m], bh[n], accA[m][n], 0, 0, 0);
        }
    }
#pragma unroll
    for (int m = 0; m < 2; ++m)
#pragma unroll
      for (int n = 0; n < 2; ++n)
#pragma unroll
        for (int j = 0; j < 4; ++j) {
          int row = ww * 32 + m * 16 + frow + j;
          int col = wv * 32 + n * 16 + fcol;
          float v = accA[m][n][j];
          unsigned short hi = f2bf(v);
          st_sw(QH, row, col, hi);
          st_sw(QL, row, col, f2bf(v - bf2f(hi)));
        }
    __syncthreads();

    f32x4 accB[2][2];
#pragma unroll
    for (int m = 0; m < 2; ++m)
#pragma unroll
      for (int n = 0; n < 2; ++n) accB[m][n] = {};
#pragma unroll
    for (int kk = 0; kk < 128; kk += 32) {
      bf16x8 ah[2], al[2], bh[2], bl[2];
#pragma unroll
      for (int m = 0; m < 2; ++m) {
        ah[m] = ld_sw(QH, ww * 32 + m * 16 + lrow, kk + lk8);
        al[m] = ld_sw(QL, ww * 32 + m * 16 + lrow, kk + lk8);
      }
#pragma unroll
      for (int n = 0; n < 2; ++n) {
        bh[n] = ld_sw(QH, wv * 32 + n * 16 + lrow, kk + lk8);
        bl[n] = ld_sw(QL, wv * 32 + n * 16 + lrow, kk + lk8);
      }
#pragma unroll
      for (int m = 0; m < 2; ++m)
#pragma unroll
        for (int n = 0; n < 2; ++n) {
          accB[m][n] = __builtin_amdgcn_mfma_f32_16x16x32_bf16(ah[m], bh[n], accB[m][n], 0, 0, 0);
          accB[m][n] = __builtin_amdgcn_mfma_f32_16x16x32_bf16(ah[m], bl[n], accB[m][n], 0, 0, 0);
          accB[m][n] = __builtin_amdgcn_mfma_f32_16x16x32_bf16(al[m], bh[n], accB[m][n], 0, 0, 0);
        }
    }
#pragma unroll
    for (int m = 0; m < 2; ++m)
#pragma unroll
      for (int n = 0; n < 2; ++n)
#pragma unroll
        for (int j = 0; j < 4; ++j)
          accB[m][n][j] = fmaf(bc, accA[m][n][j], cc2 * accB[m][n][j]);
    __syncthreads();
#pragma unroll
    for (int m = 0; m < 2; ++m)
#pragma unroll
      for (int n = 0; n < 2; ++n)
#pragma unroll
        for (int j = 0; j < 4; ++j) {
          int row = ww * 32 + m * 16 + frow + j;
          int col = wv * 32 + n * 16 + fcol;
          float v = accB[m][n][j];
          unsigned short hi = f2bf(v);
          st_sw(QH, row, col, hi);
          st_sw(QL, row, col, f2bf(v - bf2f(hi)));
        }
    unsigned short th[16], tl[16];
#pragma unroll
    for (int r = 0; r < 16; ++r) {
      int idx = tid + r * 1024;
      int rr = idx >> 7, ccx = idx & 127;
      th[r] = ld_sw1(PH, rr, ccx);
      tl[r] = ld_sw1(PL, rr, ccx);
    }
    __syncthreads();
#pragma unroll
    for (int r = 0; r < 16; ++r) {
      int idx = tid + r * 1024;
      int rr = idx >> 7, ccx = idx & 127;
      st_sw(PH, ccx, rr, th[r]);
      st_sw(PL, ccx, rr, tl[r]);
    }
    __syncthreads();

    f32x4 accC[2][2];
#pragma unroll
    for (int m = 0; m < 2; ++m)
#pragma unroll
      for (int n = 0; n < 2; ++n) accC[m][n] = {};
#pragma unroll
    for (int kk = 0; kk < 128; kk += 32) {
      bf16x8 ah[2], al[2], bh[2], bl[2];
#pragma unroll
      for (int m = 0; m < 2; ++m) {
        ah[m] = ld_sw(PH, ww * 32 + m * 16 + lrow, kk + lk8);
        al[m] = ld_sw(PL, ww * 32 + m * 16 + lrow, kk + lk8);
      }
#pragma unroll
      for (int n = 0; n < 2; ++n) {
        bh[n] = ld_sw(QH, wv * 32 + n * 16 + lrow, kk + lk8);
        bl[n] = ld_sw(QL, wv * 32 + n * 16 + lrow, kk + lk8);
      }
#pragma unroll
      for (int m = 0; m < 2; ++m)
#pragma unroll
        for (int n = 0; n < 2; ++n) {
          accC[m][n] = __builtin_amdgcn_mfma_f32_16x16x32_bf16(ah[m], bh[n], accC[m][n], 0, 0, 0);
          accC[m][n] = __builtin_amdgcn_mfma_f32_16x16x32_bf16(ah[m], bl[n], accC[m][n], 0, 0, 0);
          accC[m][n] = __builtin_amdgcn_mfma_f32_16x16x32_bf16(al[m], bh[n], accC[m][n], 0, 0, 0);
        }
    }
#pragma unroll
    for (int m = 0; m < 2; ++m)
#pragma unroll
      for (int n = 0; n < 2; ++n)
#pragma unroll
        for (int j = 0; j < 4; ++j) {
          int row = ww * 32 + m * 16 + frow + j;
          int col = wv * 32 + n * 16 + fcol;
          float yv = bf2f(ld_sw1(PH, row, col)) + bf2f(ld_sw1(PL, row, col));
          accC[m][n][j] = fmaf(ac, yv, accC[m][n][j]);
        }
    __syncthreads();
#pragma unroll
    for (int m = 0; m < 2; ++m)
#pragma unroll
      for (int n = 0; n < 2; ++n)
#pragma unroll
        for (int j = 0; j < 4; ++j) {
          int row = ww * 32 + m * 16 + frow + j;
          int col = wv * 32 + n * 16 + fcol;
          float v = accC[m][n][j];
          unsigned short hi = f2bf(v);
          st_sw(PH, row, col, hi);
          st_sw(PL, row, col, f2bf(v - bf2f(hi)));
        }
    __syncthreads();
  }

  // fused apply: dw = (z==1 ? P : P^T); w += dw; renorm rows; maintain W1T.
  const int hh2 = tid >> 7, cc = tid & 127;
  float wnew[16];
#pragma unroll
  for (int r = 0; r < 16; ++r) {
    int rr = r * 8 + hh2;
    float dv = (z == 1) ? bf2f(ld_sw1(PH, rr, cc)) + bf2f(ld_sw1(PL, rr, cc))
                        : bf2f(ld_sw1(PH, cc, rr)) + bf2f(ld_sw1(PL, cc, rr));
    float wv = WW[(size_t)(zg * 128 + rr) * 128 + cc] + dv;
    wnew[r] = wv;
    float p = wave_sum64(wv * wv);
    if (l == 0) red[w * 16 + r] = p;
  }
  __syncthreads();
#pragma unroll
  for (int r = 0; r < 16; ++r) {
    int rr = r * 8 + hh2;
    float tot2 = red[w * 16 + r] + red[(w ^ 1) * 16 + r];
    float fsc = WN0[zg * 128 + rr] / (sqrtf(tot2) + 1e-5f);
    float wv = wnew[r] * fsc;
    WW[(size_t)(zg * 128 + rr) * 128 + cc] = wv;
    if (z == 1) {
      int g = zg & 15;
      W1T[((size_t)g * 128 + cc) * 128 + rr] = wv;
    }
  }
}

// ---------------------------------------------------------------- final projection (bf16 MFMA)

__global__ __launch_bounds__(256) void k_final_mfma(const unsigned short* __restrict__ U,
                                                    const unsigned short* __restrict__ Wot,
                                                    float* __restrict__ out) {
  __shared__ unsigned short Al[128 * 32];
  __shared__ unsigned short Bl[128 * 32];
  f32x4 acc[4][4];
#pragma unroll
  for (int m = 0; m < 4; ++m)
#pragma unroll
    for (int n = 0; n < 4; ++n) acc[m][n] = {};

  const int row0 = blockIdx.x * 128, col0 = blockIdx.y * 128;
  gemm_core(U, Wot, DMODEL, DMODEL, DMODEL, row0, col0, Al, Bl, acc);

  const int tid = threadIdx.x, w = tid >> 6, l = tid & 63;
  const int wr = (w >> 1) * 64, wc = (w & 1) * 64;
#pragma unroll
  for (int m = 0; m < 4; ++m)
#pragma unroll
    for (int j = 0; j < 4; ++j) {
      int t = row0 + wr + m * 16 + (l >> 4) * 4 + j;
      float* orow = out + (size_t)t * DMODEL + col0;
#pragma unroll
      for (int n = 0; n < 4; ++n)
        orow[wc + n * 16 + (l & 15)] = acc[m][n][j];
    }
}

// ---------------------------------------------------------------- launch

extern "C" void kernel_launch(void* const* d_in, const int* in_sizes, int n_in,
                              void* d_out, int out_size, void* d_ws, size_t ws_size,
                              hipStream_t stream) {
  (void)in_sizes; (void)n_in; (void)out_size;
  const float* x    = (const float*)d_in[0];
  const float* Wqkv = (const float*)d_in[1];
  const float* Wlr  = (const float*)d_in[2];
  const float* Wo   = (const float*)d_in[3];
  const float* Wsc  = (const float*)d_in[6];
  const float* bs   = (const float*)d_in[7];
  const float* lng  = (const float*)d_in[8];
  const float* lnb  = (const float*)d_in[9];
  const float* w0   = (const float*)d_in[10];
  const float* w1   = (const float*)d_in[11];
  const float* w2   = (const float*)d_in[12];

  float* Q = (float*)d_out;  // last read (k_out2 chunk 3) precedes k_final's write

  float* ws = (float*)d_ws;
  size_t off = 0;
  auto alloc = [&](size_t n) { float* p = ws + off; off += n; return p; };
  float* Km   = alloc((size_t)NH * LSEQ * HD);
  float* V    = alloc((size_t)NH * LSEQ * HD);
  float* Uf   = alloc((size_t)LSEQ * DMODEL / 2);   // U stored as bf16
  float* LR   = alloc((size_t)3 * NH * LSEQ);
  float* SCL  = alloc((size_t)NH * LSEQ);
  float* WW   = alloc((size_t)3 * NH * HD * HD);
  float* WN0  = alloc((size_t)3 * NH * HD);
  float* W1T  = alloc((size_t)NH * HD * HD);
  float* BUF  = alloc((size_t)3 * NH * HD * CH);    // chunk loop scratch
  float* DWP  = alloc((size_t)3 * NH * 8 * HD * HD);
  if (off * sizeof(float) > ws_size) return;        // clean failure instead of OOB

  unsigned short* U = (unsigned short*)Uf;
  unsigned short* xb  = (unsigned short*)BUF;                                   // pre-qkv
  unsigned short* Wqt = (unsigned short*)(BUF + (size_t)LSEQ * DMODEL / 2);
  float* Plr = BUF;                                                             // lrms partials
  unsigned short* Wot = (unsigned short*)BUF;                                   // post-loop

  k_init_w<<<3 * NH * HD, 64, 0, stream>>>(w0, w1, w2, WW, WN0, W1T);
  k_cast<<<2048, 256, 0, stream>>>(x, xb, LSEQ * DMODEL / 4);
  k_tcast<<<dim3(3 * DMODEL / 64, DMODEL / 64), 256, 0, stream>>>(Wqkv, Wqt, DMODEL, 3 * DMODEL);
  k_qkv_mfma<<<dim3(LSEQ / 128, 48), 256, 0, stream>>>(xb, Wqt, Q, Km, V);
  k_lrms5<<<dim3(LSEQ / 64, 16), 256, 0, stream>>>(x, Wlr, Wsc, Plr);
  k_lrsum<<<LSEQ * 64 / 256, 256, 0, stream>>>(Plr, bs, LR, SCL);

  for (int c = 0; c < 4; ++c) {
    int s = c * CH;
    k_out2<<<dim3(CH / 64, NH), 256, 0, stream>>>(WW, Q, SCL, lng, lnb, U, s);
    if (c < 3) {
      k_fe<<<dim3(CH / 128, NH), 1024, 0, stream>>>(WW, W1T, Km, V, BUF, s);
      k_dwp_mx<<<dim3(8, NH, 3), 256, 0, stream>>>(BUF, Km, V, LR, DWP, s);
      k_ns5_mfma<<<3 * NH, 1024, 0, stream>>>(DWP, WW, WN0, W1T);
    }
  }
  k_tcast<<<dim3(DMODEL / 64, DMODEL / 64), 256, 0, stream>>>(Wo, Wot, DMODEL, DMODEL);
  k_final_mfma<<<dim3(LSEQ / 128, DMODEL / 128), 256, 0, stream>>>(U, Wot, (float*)d_out);
}